// Round 1
// baseline (5852.178 us; speedup 1.0000x reference)
//
#include <hip/hip_runtime.h>

#define IN_DIM 128
#define OUT_DIM 128

// ---------------------------------------------------------------------------
// Kernel 1: H = X @ W   (fp32, W column held in registers per thread)
// thread t: column j = t & 127; two row-streams per block (t>>7).
// All 64 lanes of a wave share the same row -> X loads are same-address
// broadcasts served from L1. W[:,j] loaded once per thread (coalesced).
// ---------------------------------------------------------------------------
__global__ __launch_bounds__(256) void gemm_xw(const float* __restrict__ X,
                                               const float* __restrict__ W,
                                               float* __restrict__ H,
                                               int n_rows) {
    const int j = threadIdx.x & 127;    // output column
    const int rsub = threadIdx.x >> 7;  // 0 or 1

    float w[IN_DIM];
#pragma unroll
    for (int k = 0; k < IN_DIM; ++k) w[k] = W[k * OUT_DIM + j];

    for (long long r = (long long)blockIdx.x * 2 + rsub; r < n_rows;
         r += (long long)gridDim.x * 2) {
        const float4* xr = (const float4*)(X + r * IN_DIM);
        float acc = 0.0f;
#pragma unroll
        for (int c = 0; c < IN_DIM / 4; ++c) {
            float4 xv = xr[c];
            acc += xv.x * w[4 * c + 0];
            acc += xv.y * w[4 * c + 1];
            acc += xv.z * w[4 * c + 2];
            acc += xv.w * w[4 * c + 3];
        }
        H[r * OUT_DIM + j] = acc;
    }
}

// ---------------------------------------------------------------------------
// Kernel 2: out[i][j] = bias[j]   (d_out is poisoned 0xAA before every call)
// One float4 per thread, exact-size grid.
// ---------------------------------------------------------------------------
__global__ __launch_bounds__(256) void bias_init(const float* __restrict__ bias,
                                                 float* __restrict__ out,
                                                 long long n_vec4) {
    long long i = (long long)blockIdx.x * 256 + threadIdx.x;
    if (i < n_vec4) {
        float4 b = ((const float4*)bias)[i & (OUT_DIM / 4 - 1)];
        ((float4*)out)[i] = b;
    }
}

// ---------------------------------------------------------------------------
// Kernel 3: out[dst] += val * H[src]   — edge-parallel, 32 threads/edge,
// float4 gather + 4 scalar f32 atomics per thread.
// ---------------------------------------------------------------------------
__global__ __launch_bounds__(256) void edge_scatter(const int* __restrict__ src,
                                                    const int* __restrict__ dst,
                                                    const float* __restrict__ vals,
                                                    const float* __restrict__ H,
                                                    float* __restrict__ out,
                                                    long long n_edges) {
    long long idx = (long long)blockIdx.x * 256 + threadIdx.x;
    long long e = idx >> 5;  // 32 threads per edge
    int q = (int)(idx & 31); // which float4 of the 128-wide row
    if (e >= n_edges) return;

    int s = src[e];
    int d = dst[e];
    float v = vals[e];

    float4 h = ((const float4*)(H + (long long)s * OUT_DIM))[q];
    float* o = out + (long long)d * OUT_DIM + q * 4;
    atomicAdd(o + 0, h.x * v);
    atomicAdd(o + 1, h.y * v);
    atomicAdd(o + 2, h.z * v);
    atomicAdd(o + 3, h.w * v);
}

extern "C" void kernel_launch(void* const* d_in, const int* in_sizes, int n_in,
                              void* d_out, int out_size, void* d_ws, size_t ws_size,
                              hipStream_t stream) {
    const float* features = (const float*)d_in[0];
    const int* edge_src   = (const int*)d_in[1];
    const int* edge_dst   = (const int*)d_in[2];
    const float* edge_vals = (const float*)d_in[3];
    const float* weight   = (const float*)d_in[4];
    const float* bias     = (const float*)d_in[5];

    const int n_nodes = in_sizes[0] / IN_DIM;
    const long long n_edges = in_sizes[1];

    float* H = (float*)d_ws;  // n_nodes * OUT_DIM floats (51.2 MB)
    float* out = (float*)d_out;

    // 1) H = X @ W
    gemm_xw<<<1024, 256, 0, stream>>>(features, weight, H, n_nodes);

    // 2) out = bias (broadcast); also wipes the 0xAA poison
    long long n_vec4 = (long long)n_nodes * (OUT_DIM / 4);
    int bgrid = (int)((n_vec4 + 255) / 256);
    bias_init<<<bgrid, 256, 0, stream>>>(bias, out, n_vec4);

    // 3) out[dst] += val * H[src]
    long long n_thr = n_edges * 32;
    int egrid = (int)((n_thr + 255) / 256);
    edge_scatter<<<egrid, 256, 0, stream>>>(edge_src, edge_dst, edge_vals, H,
                                            out, n_edges);
}

// Round 2
// 1306.832 us; speedup vs baseline: 4.4781x; 4.4781x over previous
//
#include <hip/hip_runtime.h>

#define IN_DIM 128
#define OUT_DIM 128
#define N_SCAN_THREADS 1024

// ---------------------------------------------------------------------------
// Kernel 1: H = X @ W   (fp32, W column held in registers per thread)
// ---------------------------------------------------------------------------
__global__ __launch_bounds__(256) void gemm_xw(const float* __restrict__ X,
                                               const float* __restrict__ W,
                                               float* __restrict__ H,
                                               int n_rows) {
    const int j = threadIdx.x & 127;    // output column
    const int rsub = threadIdx.x >> 7;  // 0 or 1

    float w[IN_DIM];
#pragma unroll
    for (int k = 0; k < IN_DIM; ++k) w[k] = W[k * OUT_DIM + j];

    for (long long r = (long long)blockIdx.x * 2 + rsub; r < n_rows;
         r += (long long)gridDim.x * 2) {
        const float4* xr = (const float4*)(X + r * IN_DIM);
        float acc = 0.0f;
#pragma unroll
        for (int c = 0; c < IN_DIM / 4; ++c) {
            float4 xv = xr[c];
            acc += xv.x * w[4 * c + 0];
            acc += xv.y * w[4 * c + 1];
            acc += xv.z * w[4 * c + 2];
            acc += xv.w * w[4 * c + 3];
        }
        H[r * OUT_DIM + j] = acc;
    }
}

// ---------------------------------------------------------------------------
// CSR build: zero counters -> histogram -> scan -> scatter
// ---------------------------------------------------------------------------
__global__ __launch_bounds__(256) void zero_ints(int* __restrict__ p, int n) {
    int i = blockIdx.x * 256 + threadIdx.x;
    if (i < n) p[i] = 0;
}

__global__ __launch_bounds__(256) void hist_dst(const int* __restrict__ dst,
                                                int* __restrict__ cnt,
                                                int n_edges) {
    int i = blockIdx.x * 256 + threadIdx.x;
    if (i < n_edges) atomicAdd(&cnt[dst[i]], 1);
}

// Single workgroup exclusive scan over n counters.
// Input counts live in `cursor`; writes row_ptr[0..n] and rewrites cursor[i]
// to the running start offset (so scatter can atomically bump it).
__global__ __launch_bounds__(N_SCAN_THREADS) void scan_counts(
    int* __restrict__ cursor, int* __restrict__ row_ptr, int n) {
    __shared__ int sdata[N_SCAN_THREADS];
    const int tid = threadIdx.x;
    const int chunk = (n + N_SCAN_THREADS - 1) / N_SCAN_THREADS;
    const int beg = tid * chunk;
    const int end = min(n, beg + chunk);

    int sum = 0;
    for (int i = beg; i < end; ++i) sum += cursor[i];
    sdata[tid] = sum;
    __syncthreads();

    for (int off = 1; off < N_SCAN_THREADS; off <<= 1) {
        int v = (tid >= off) ? sdata[tid - off] : 0;
        __syncthreads();
        sdata[tid] += v;
        __syncthreads();
    }

    int run = sdata[tid] - sum;  // exclusive prefix for this thread's chunk
    for (int i = beg; i < end; ++i) {
        int c = cursor[i];
        row_ptr[i] = run;
        cursor[i] = run;
        run += c;
    }
    if (tid == N_SCAN_THREADS - 1) row_ptr[n] = sdata[N_SCAN_THREADS - 1];
}

__global__ __launch_bounds__(256) void scatter_edges(
    const int* __restrict__ src, const int* __restrict__ dst,
    const float* __restrict__ vals, int* __restrict__ cursor,
    int* __restrict__ csr_src, float* __restrict__ csr_val, int n_edges) {
    int i = blockIdx.x * 256 + threadIdx.x;
    if (i < n_edges) {
        int d = dst[i];
        int pos = atomicAdd(&cursor[d], 1);
        csr_src[pos] = src[i];
        csr_val[pos] = vals[i];
    }
}

// ---------------------------------------------------------------------------
// Gather-reduce: one wave per dst node; lane holds 2 output columns.
// out[d] = bias + sum_e val_e * H[src_e]
// ---------------------------------------------------------------------------
__global__ __launch_bounds__(256) void gather_nodes(
    const int* __restrict__ row_ptr, const int* __restrict__ csr_src,
    const float* __restrict__ csr_val, const float* __restrict__ H,
    const float* __restrict__ bias, float* __restrict__ out, int n_nodes) {
    int node = blockIdx.x * 4 + (threadIdx.x >> 6);
    if (node >= n_nodes) return;
    int lane = threadIdx.x & 63;

    int beg = row_ptr[node];
    int end = row_ptr[node + 1];

    float2 acc = ((const float2*)bias)[lane];

    int e = beg;
    for (; e + 2 <= end; e += 2) {
        int s0 = csr_src[e];
        int s1 = csr_src[e + 1];
        float v0 = csr_val[e];
        float v1 = csr_val[e + 1];
        float2 h0 = ((const float2*)(H + (long long)s0 * OUT_DIM))[lane];
        float2 h1 = ((const float2*)(H + (long long)s1 * OUT_DIM))[lane];
        acc.x += v0 * h0.x + v1 * h1.x;
        acc.y += v0 * h0.y + v1 * h1.y;
    }
    if (e < end) {
        int s0 = csr_src[e];
        float v0 = csr_val[e];
        float2 h0 = ((const float2*)(H + (long long)s0 * OUT_DIM))[lane];
        acc.x += v0 * h0.x;
        acc.y += v0 * h0.y;
    }

    ((float2*)(out + (long long)node * OUT_DIM))[lane] = acc;
}

extern "C" void kernel_launch(void* const* d_in, const int* in_sizes, int n_in,
                              void* d_out, int out_size, void* d_ws, size_t ws_size,
                              hipStream_t stream) {
    const float* features  = (const float*)d_in[0];
    const int* edge_src    = (const int*)d_in[1];
    const int* edge_dst    = (const int*)d_in[2];
    const float* edge_vals = (const float*)d_in[3];
    const float* weight    = (const float*)d_in[4];
    const float* bias      = (const float*)d_in[5];

    const int n_nodes = in_sizes[0] / IN_DIM;
    const int n_edges = in_sizes[1];

    // workspace layout (all 4-byte types)
    float* H       = (float*)d_ws;                       // n_nodes*128 floats
    int* row_ptr   = (int*)(H + (long long)n_nodes * OUT_DIM);  // n_nodes+1
    int* cursor    = row_ptr + (n_nodes + 2);            // n_nodes
    int* csr_src   = cursor + n_nodes;                   // n_edges
    float* csr_val = (float*)(csr_src + n_edges);        // n_edges

    float* out = (float*)d_out;

    const int egrid = (n_edges + 255) / 256;
    const int ngrid = (n_nodes + 255) / 256;

    // CSR build
    zero_ints<<<ngrid, 256, 0, stream>>>(cursor, n_nodes);
    hist_dst<<<egrid, 256, 0, stream>>>(edge_dst, cursor, n_edges);
    scan_counts<<<1, N_SCAN_THREADS, 0, stream>>>(cursor, row_ptr, n_nodes);
    scatter_edges<<<egrid, 256, 0, stream>>>(edge_src, edge_dst, edge_vals,
                                             cursor, csr_src, csr_val, n_edges);

    // H = X @ W (independent of CSR build)
    gemm_xw<<<1024, 256, 0, stream>>>(features, weight, H, n_nodes);

    // out = bias + sum over incoming edges
    gather_nodes<<<(n_nodes + 3) / 4, 256, 0, stream>>>(
        row_ptr, csr_src, csr_val, H, bias, out, n_nodes);
}

// Round 3
// 743.510 us; speedup vs baseline: 7.8710x; 1.7577x over previous
//
#include <hip/hip_runtime.h>

#define IN_DIM 128
#define OUT_DIM 128
#define SCAN_B 1024

typedef __attribute__((ext_vector_type(8))) short bf16x8;
typedef __attribute__((ext_vector_type(4))) float f32x4;

__device__ inline short f2bf(float f) {
    unsigned u = __float_as_uint(f);
    unsigned r = (u + 0x7fff + ((u >> 16) & 1)) >> 16;  // RNE
    return (short)r;
}

// ---------------------------------------------------------------------------
// X (fp32) -> Xb (bf16), 8 elements/thread
// ---------------------------------------------------------------------------
__global__ __launch_bounds__(256) void convert_x(const float* __restrict__ X,
                                                 short* __restrict__ Xb,
                                                 long long n8) {
    long long i = (long long)blockIdx.x * 256 + threadIdx.x;
    if (i >= n8) return;
    float4 a = ((const float4*)X)[2 * i];
    float4 b = ((const float4*)X)[2 * i + 1];
    bf16x8 o;
    o[0] = f2bf(a.x); o[1] = f2bf(a.y); o[2] = f2bf(a.z); o[3] = f2bf(a.w);
    o[4] = f2bf(b.x); o[5] = f2bf(b.y); o[6] = f2bf(b.z); o[7] = f2bf(b.w);
    ((bf16x8*)Xb)[i] = o;
}

// ---------------------------------------------------------------------------
// Pack W[k][n] (128x128 fp32) into B-fragment order, bf16:
// Wpack[((tn*4+kc)*64+lane)*8 + j] = W[kc*32 + (lane>>4)*8 + j][tn*16 + (lane&15)]
// ---------------------------------------------------------------------------
__global__ __launch_bounds__(256) void pack_w(const float* __restrict__ W,
                                              short* __restrict__ Wpack) {
    for (int idx = threadIdx.x; idx < 16384; idx += 256) {
        int j = idx & 7;
        int lane = (idx >> 3) & 63;
        int kc = (idx >> 9) & 3;
        int tn = idx >> 11;
        int k = kc * 32 + (lane >> 4) * 8 + j;
        int n = tn * 16 + (lane & 15);
        Wpack[idx] = f2bf(W[k * OUT_DIM + n]);
    }
}

// ---------------------------------------------------------------------------
// H = Xb @ Wpack via MFMA 16x16x32 bf16. One wave = 32 rows x 128 cols.
// ---------------------------------------------------------------------------
__global__ __launch_bounds__(256) void gemm_mfma(const short* __restrict__ Xb,
                                                 const short* __restrict__ Wpack,
                                                 float* __restrict__ H,
                                                 int n_strips) {
    int strip = blockIdx.x * 4 + (threadIdx.x >> 6);
    if (strip >= n_strips) return;
    int lane = threadIdx.x & 63;
    int quad = lane >> 4;
    int low = lane & 15;
    long long m0 = (long long)strip * 32;

    const bf16x8* A = (const bf16x8*)Xb;     // index = row*16 + kc*4 + quad
    const bf16x8* B = (const bf16x8*)Wpack;  // index = (tn*4+kc)*64 + lane

    f32x4 acc[2][8] = {};

    long long a0base = (m0 + low) * 16 + quad;
    long long a1base = (m0 + 16 + low) * 16 + quad;

#pragma unroll
    for (int kc = 0; kc < 4; ++kc) {
        bf16x8 afr0 = A[a0base + kc * 4];
        bf16x8 afr1 = A[a1base + kc * 4];
#pragma unroll
        for (int tn = 0; tn < 8; ++tn) {
            bf16x8 bfr = B[(tn * 4 + kc) * 64 + lane];
            acc[0][tn] = __builtin_amdgcn_mfma_f32_16x16x32_bf16(afr0, bfr, acc[0][tn], 0, 0, 0);
            acc[1][tn] = __builtin_amdgcn_mfma_f32_16x16x32_bf16(afr1, bfr, acc[1][tn], 0, 0, 0);
        }
    }

#pragma unroll
    for (int t = 0; t < 2; ++t) {
#pragma unroll
        for (int tn = 0; tn < 8; ++tn) {
#pragma unroll
            for (int r = 0; r < 4; ++r) {
                long long row = m0 + t * 16 + quad * 4 + r;
                int col = tn * 16 + low;
                H[row * OUT_DIM + col] = acc[t][tn][r];
            }
        }
    }
}

// ---------------------------------------------------------------------------
// CSR build
// ---------------------------------------------------------------------------
__global__ __launch_bounds__(256) void zero_ints(int* __restrict__ p, int n) {
    int i = blockIdx.x * 256 + threadIdx.x;
    if (i < n) p[i] = 0;
}

__global__ __launch_bounds__(256) void hist_dst(const int* __restrict__ dst,
                                                int* __restrict__ cnt,
                                                int n_edges) {
    int i = blockIdx.x * 256 + threadIdx.x;
    if (i < n_edges) atomicAdd(&cnt[dst[i]], 1);
}

// 3-phase coalesced exclusive scan: A) per-block scan, B) scan block sums,
// C) add offsets, write row_ptr + cursor.
__global__ __launch_bounds__(SCAN_B) void scan_phaseA(const int* __restrict__ cnt,
                                                      int* __restrict__ pre,
                                                      int* __restrict__ bsums,
                                                      int n) {
    __shared__ int s[SCAN_B];
    int tid = threadIdx.x;
    int i = blockIdx.x * SCAN_B + tid;
    int v = (i < n) ? cnt[i] : 0;
    s[tid] = v;
    __syncthreads();
    for (int off = 1; off < SCAN_B; off <<= 1) {
        int t = (tid >= off) ? s[tid - off] : 0;
        __syncthreads();
        s[tid] += t;
        __syncthreads();
    }
    if (i < n) pre[i] = s[tid] - v;
    if (tid == SCAN_B - 1) bsums[blockIdx.x] = s[tid];
}

__global__ __launch_bounds__(SCAN_B) void scan_phaseB(int* __restrict__ bsums,
                                                      int* __restrict__ row_ptr,
                                                      int nb, int n) {
    __shared__ int s[SCAN_B];
    int tid = threadIdx.x;
    int v = (tid < nb) ? bsums[tid] : 0;
    s[tid] = v;
    __syncthreads();
    for (int off = 1; off < SCAN_B; off <<= 1) {
        int t = (tid >= off) ? s[tid - off] : 0;
        __syncthreads();
        s[tid] += t;
        __syncthreads();
    }
    if (tid < nb) bsums[tid] = s[tid] - v;
    if (tid == SCAN_B - 1) row_ptr[n] = s[tid];
}

__global__ __launch_bounds__(256) void scan_phaseC(int* __restrict__ row_ptr,
                                                   int* __restrict__ cursor,
                                                   const int* __restrict__ bsums,
                                                   int n) {
    int i = blockIdx.x * 256 + threadIdx.x;
    if (i < n) {
        int v = row_ptr[i] + bsums[i >> 10];
        row_ptr[i] = v;
        cursor[i] = v;
    }
}

__global__ __launch_bounds__(256) void scatter_edges(
    const int* __restrict__ src, const int* __restrict__ dst,
    const float* __restrict__ vals, int* __restrict__ cursor,
    int* __restrict__ csr_src, float* __restrict__ csr_val, int n_edges) {
    int i = blockIdx.x * 256 + threadIdx.x;
    if (i < n_edges) {
        int d = dst[i];
        int pos = atomicAdd(&cursor[d], 1);
        csr_src[pos] = src[i];
        csr_val[pos] = vals[i];
    }
}

// ---------------------------------------------------------------------------
// Gather-reduce: one wave per dst node; lane holds 2 output columns.
// ---------------------------------------------------------------------------
__global__ __launch_bounds__(256) void gather_nodes(
    const int* __restrict__ row_ptr, const int* __restrict__ csr_src,
    const float* __restrict__ csr_val, const float* __restrict__ H,
    const float* __restrict__ bias, float* __restrict__ out, int n_nodes) {
    int node = blockIdx.x * 4 + (threadIdx.x >> 6);
    if (node >= n_nodes) return;
    int lane = threadIdx.x & 63;

    int beg = row_ptr[node];
    int end = row_ptr[node + 1];

    float2 acc = ((const float2*)bias)[lane];

    int e = beg;
    for (; e + 2 <= end; e += 2) {
        int s0 = csr_src[e];
        int s1 = csr_src[e + 1];
        float v0 = csr_val[e];
        float v1 = csr_val[e + 1];
        float2 h0 = ((const float2*)(H + (long long)s0 * OUT_DIM))[lane];
        float2 h1 = ((const float2*)(H + (long long)s1 * OUT_DIM))[lane];
        acc.x += v0 * h0.x + v1 * h1.x;
        acc.y += v0 * h0.y + v1 * h1.y;
    }
    if (e < end) {
        int s0 = csr_src[e];
        float v0 = csr_val[e];
        float2 h0 = ((const float2*)(H + (long long)s0 * OUT_DIM))[lane];
        acc.x += v0 * h0.x;
        acc.y += v0 * h0.y;
    }

    ((float2*)(out + (long long)node * OUT_DIM))[lane] = acc;
}

extern "C" void kernel_launch(void* const* d_in, const int* in_sizes, int n_in,
                              void* d_out, int out_size, void* d_ws, size_t ws_size,
                              hipStream_t stream) {
    const float* features  = (const float*)d_in[0];
    const int* edge_src    = (const int*)d_in[1];
    const int* edge_dst    = (const int*)d_in[2];
    const float* edge_vals = (const float*)d_in[3];
    const float* weight    = (const float*)d_in[4];
    const float* bias      = (const float*)d_in[5];

    const int n_nodes = in_sizes[0] / IN_DIM;
    const int n_edges = in_sizes[1];

    // workspace layout
    float* H       = (float*)d_ws;                            // 12.8M floats
    short* Xb      = (short*)(H + (long long)n_nodes * OUT_DIM);  // 12.8M bf16
    short* Wpack   = Xb + (long long)n_nodes * IN_DIM;        // 16384 bf16
    int* row_ptr   = (int*)(Wpack + 16384);                   // n_nodes+1
    int* cursor    = row_ptr + (n_nodes + 2);                 // n_nodes
    int* bsums     = cursor + n_nodes;                        // <=1024
    int* csr_src   = bsums + SCAN_B;                          // n_edges
    float* csr_val = (float*)(csr_src + n_edges);             // n_edges

    float* out = (float*)d_out;

    const int egrid = (n_edges + 255) / 256;
    const int ngrid = (n_nodes + 255) / 256;
    const int nscan = (n_nodes + SCAN_B - 1) / SCAN_B;

    // CSR build
    zero_ints<<<ngrid, 256, 0, stream>>>(cursor, n_nodes);
    hist_dst<<<egrid, 256, 0, stream>>>(edge_dst, cursor, n_edges);
    scan_phaseA<<<nscan, SCAN_B, 0, stream>>>(cursor, row_ptr, bsums, n_nodes);
    scan_phaseB<<<1, SCAN_B, 0, stream>>>(bsums, row_ptr, nscan, n_nodes);
    scan_phaseC<<<ngrid, 256, 0, stream>>>(row_ptr, cursor, bsums, n_nodes);
    scatter_edges<<<egrid, 256, 0, stream>>>(edge_src, edge_dst, edge_vals,
                                             cursor, csr_src, csr_val, n_edges);

    // H = X @ W  (bf16 MFMA)
    long long n8 = (long long)n_nodes * IN_DIM / 8;
    convert_x<<<(int)((n8 + 255) / 256), 256, 0, stream>>>(features, Xb, n8);
    pack_w<<<1, 256, 0, stream>>>(weight, Wpack);
    int n_strips = (n_nodes + 31) / 32;
    gemm_mfma<<<(n_strips + 3) / 4, 256, 0, stream>>>(Xb, Wpack, H, n_strips);

    // out = bias + sum over incoming edges
    gather_nodes<<<(n_nodes + 3) / 4, 256, 0, stream>>>(
        row_ptr, csr_src, csr_val, H, bias, out, n_nodes);
}

// Round 4
// 558.231 us; speedup vs baseline: 10.4834x; 1.3319x over previous
//
#include <hip/hip_runtime.h>

#define IN_DIM 128
#define OUT_DIM 128
#define SCAN_B 1024

typedef __attribute__((ext_vector_type(8))) short bf16x8;
typedef __attribute__((ext_vector_type(4))) float f32x4;

__device__ inline unsigned short f2bf(float f) {
    unsigned u = __float_as_uint(f);
    unsigned r = (u + 0x7fff + ((u >> 16) & 1)) >> 16;  // RNE
    return (unsigned short)r;
}
__device__ inline float bflo(unsigned h) { return __uint_as_float(h << 16); }
__device__ inline float bfhi(unsigned h) { return __uint_as_float(h & 0xffff0000u); }

// ---------------------------------------------------------------------------
// Pack W[k][n] (128x128 fp32) into B-fragment order, bf16 (parallel, 64 blocks)
// Wpack[((tn*4+kc)*64+lane)*8 + j] = W[kc*32 + (lane>>4)*8 + j][tn*16 + (lane&15)]
// ---------------------------------------------------------------------------
__global__ __launch_bounds__(256) void pack_w(const float* __restrict__ W,
                                              unsigned short* __restrict__ Wpack) {
    int idx = blockIdx.x * 256 + threadIdx.x;
    if (idx >= 16384) return;
    int j = idx & 7;
    int lane = (idx >> 3) & 63;
    int kc = (idx >> 9) & 3;
    int tn = idx >> 11;
    int k = kc * 32 + (lane >> 4) * 8 + j;
    int n = tn * 16 + (lane & 15);
    Wpack[idx] = f2bf(W[k * OUT_DIM + n]);
}

// ---------------------------------------------------------------------------
// Hb = bf16( X @ W ) via MFMA 16x16x32 bf16. One wave = 32 rows x 128 cols.
// X read directly in fp32, converted in-register (no separate convert pass).
// ---------------------------------------------------------------------------
__global__ __launch_bounds__(256) void gemm_mfma(const float* __restrict__ X,
                                                 const unsigned short* __restrict__ Wpack,
                                                 unsigned short* __restrict__ Hb,
                                                 int n_rows) {
    int strip = blockIdx.x * 4 + (threadIdx.x >> 6);
    long long m0 = (long long)strip * 32;
    if (m0 >= n_rows) return;
    int lane = threadIdx.x & 63;
    int quad = lane >> 4;
    int low = lane & 15;

    const bf16x8* B = (const bf16x8*)Wpack;  // index = (tn*4+kc)*64 + lane

    long long r0 = m0 + low;
    long long r1 = m0 + 16 + low;
    if (r1 >= n_rows) r1 = n_rows - 1;  // clamp (dup compute, stores guarded)
    if (r0 >= n_rows) r0 = n_rows - 1;

    f32x4 acc[2][8] = {};

#pragma unroll
    for (int kc = 0; kc < 4; ++kc) {
        // A fragment: X[row][kc*32 + quad*8 .. +8]
        const float4* p0 = (const float4*)(X + r0 * IN_DIM + kc * 32 + quad * 8);
        const float4* p1 = (const float4*)(X + r1 * IN_DIM + kc * 32 + quad * 8);
        float4 x0a = p0[0], x0b = p0[1];
        float4 x1a = p1[0], x1b = p1[1];
        bf16x8 afr0, afr1;
        afr0[0] = f2bf(x0a.x); afr0[1] = f2bf(x0a.y); afr0[2] = f2bf(x0a.z); afr0[3] = f2bf(x0a.w);
        afr0[4] = f2bf(x0b.x); afr0[5] = f2bf(x0b.y); afr0[6] = f2bf(x0b.z); afr0[7] = f2bf(x0b.w);
        afr1[0] = f2bf(x1a.x); afr1[1] = f2bf(x1a.y); afr1[2] = f2bf(x1a.z); afr1[3] = f2bf(x1a.w);
        afr1[4] = f2bf(x1b.x); afr1[5] = f2bf(x1b.y); afr1[6] = f2bf(x1b.z); afr1[7] = f2bf(x1b.w);
#pragma unroll
        for (int tn = 0; tn < 8; ++tn) {
            bf16x8 bfr = B[(tn * 4 + kc) * 64 + lane];
            acc[0][tn] = __builtin_amdgcn_mfma_f32_16x16x32_bf16(afr0, bfr, acc[0][tn], 0, 0, 0);
            acc[1][tn] = __builtin_amdgcn_mfma_f32_16x16x32_bf16(afr1, bfr, acc[1][tn], 0, 0, 0);
        }
    }

#pragma unroll
    for (int t = 0; t < 2; ++t) {
#pragma unroll
        for (int tn = 0; tn < 8; ++tn) {
#pragma unroll
            for (int r = 0; r < 4; ++r) {
                long long row = m0 + t * 16 + quad * 4 + r;
                if (row < n_rows) {
                    int col = tn * 16 + low;
                    Hb[row * OUT_DIM + col] = f2bf(acc[t][tn][r]);
                }
            }
        }
    }
}

// ---------------------------------------------------------------------------
// CSR build: zero -> histogram -> 3-phase scan -> scatter (int2 interleaved)
// ---------------------------------------------------------------------------
__global__ __launch_bounds__(256) void zero_ints(int* __restrict__ p, int n) {
    int i = blockIdx.x * 256 + threadIdx.x;
    if (i < n) p[i] = 0;
}

__global__ __launch_bounds__(256) void hist_dst(const int* __restrict__ dst,
                                                int* __restrict__ cnt,
                                                int n_edges) {
    int i = blockIdx.x * 256 + threadIdx.x;
    if (i < n_edges) atomicAdd(&cnt[dst[i]], 1);
}

__global__ __launch_bounds__(SCAN_B) void scan_phaseA(const int* __restrict__ cnt,
                                                      int* __restrict__ pre,
                                                      int* __restrict__ bsums,
                                                      int n) {
    __shared__ int s[SCAN_B];
    int tid = threadIdx.x;
    int i = blockIdx.x * SCAN_B + tid;
    int v = (i < n) ? cnt[i] : 0;
    s[tid] = v;
    __syncthreads();
    for (int off = 1; off < SCAN_B; off <<= 1) {
        int t = (tid >= off) ? s[tid - off] : 0;
        __syncthreads();
        s[tid] += t;
        __syncthreads();
    }
    if (i < n) pre[i] = s[tid] - v;
    if (tid == SCAN_B - 1) bsums[blockIdx.x] = s[tid];
}

__global__ __launch_bounds__(SCAN_B) void scan_phaseB(int* __restrict__ bsums,
                                                      int* __restrict__ row_ptr,
                                                      int nb, int n) {
    __shared__ int s[SCAN_B];
    int tid = threadIdx.x;
    int v = (tid < nb) ? bsums[tid] : 0;
    s[tid] = v;
    __syncthreads();
    for (int off = 1; off < SCAN_B; off <<= 1) {
        int t = (tid >= off) ? s[tid - off] : 0;
        __syncthreads();
        s[tid] += t;
        __syncthreads();
    }
    if (tid < nb) bsums[tid] = s[tid] - v;
    if (tid == SCAN_B - 1) row_ptr[n] = s[tid];
}

__global__ __launch_bounds__(256) void scan_phaseC(int* __restrict__ row_ptr,
                                                   int* __restrict__ cursor,
                                                   const int* __restrict__ bsums,
                                                   int n) {
    int i = blockIdx.x * 256 + threadIdx.x;
    if (i < n) {
        int v = row_ptr[i] + bsums[i >> 10];
        row_ptr[i] = v;
        cursor[i] = v;
    }
}

__global__ __launch_bounds__(256) void scatter_edges(
    const int* __restrict__ src, const int* __restrict__ dst,
    const float* __restrict__ vals, int* __restrict__ cursor,
    int2* __restrict__ csr, int n_edges) {
    int i = blockIdx.x * 256 + threadIdx.x;
    if (i < n_edges) {
        int d = dst[i];
        int pos = atomicAdd(&cursor[d], 1);
        csr[pos] = make_int2(src[i], __float_as_int(vals[i]));
    }
}

// ---------------------------------------------------------------------------
// Gather-reduce: one wave per dst node; lane holds 2 output columns (bf16 H).
// out[d] = bias + sum_e val_e * Hb[src_e]
// ---------------------------------------------------------------------------
__global__ __launch_bounds__(256) void gather_nodes(
    const int* __restrict__ row_ptr, const int2* __restrict__ csr,
    const unsigned short* __restrict__ Hb, const float* __restrict__ bias,
    float* __restrict__ out, int n_nodes) {
    int node = blockIdx.x * 4 + (threadIdx.x >> 6);
    if (node >= n_nodes) return;
    int lane = threadIdx.x & 63;

    int beg = row_ptr[node];
    int end = row_ptr[node + 1];

    float2 acc = ((const float2*)bias)[lane];

    int e = beg;
    for (; e + 4 <= end; e += 4) {
        int2 c0 = csr[e + 0];
        int2 c1 = csr[e + 1];
        int2 c2 = csr[e + 2];
        int2 c3 = csr[e + 3];
        unsigned h0 = *(const unsigned*)(Hb + (long long)c0.x * OUT_DIM + lane * 2);
        unsigned h1 = *(const unsigned*)(Hb + (long long)c1.x * OUT_DIM + lane * 2);
        unsigned h2 = *(const unsigned*)(Hb + (long long)c2.x * OUT_DIM + lane * 2);
        unsigned h3 = *(const unsigned*)(Hb + (long long)c3.x * OUT_DIM + lane * 2);
        float v0 = __int_as_float(c0.y);
        float v1 = __int_as_float(c1.y);
        float v2 = __int_as_float(c2.y);
        float v3 = __int_as_float(c3.y);
        acc.x += v0 * bflo(h0) + v1 * bflo(h1) + v2 * bflo(h2) + v3 * bflo(h3);
        acc.y += v0 * bfhi(h0) + v1 * bfhi(h1) + v2 * bfhi(h2) + v3 * bfhi(h3);
    }
    for (; e < end; ++e) {
        int2 c0 = csr[e];
        unsigned h0 = *(const unsigned*)(Hb + (long long)c0.x * OUT_DIM + lane * 2);
        float v0 = __int_as_float(c0.y);
        acc.x += v0 * bflo(h0);
        acc.y += v0 * bfhi(h0);
    }

    ((float2*)(out + (long long)node * OUT_DIM))[lane] = acc;
}

extern "C" void kernel_launch(void* const* d_in, const int* in_sizes, int n_in,
                              void* d_out, int out_size, void* d_ws, size_t ws_size,
                              hipStream_t stream) {
    const float* features  = (const float*)d_in[0];
    const int* edge_src    = (const int*)d_in[1];
    const int* edge_dst    = (const int*)d_in[2];
    const float* edge_vals = (const float*)d_in[3];
    const float* weight    = (const float*)d_in[4];
    const float* bias      = (const float*)d_in[5];

    const int n_nodes = in_sizes[0] / IN_DIM;
    const int n_edges = in_sizes[1];

    // workspace layout (csr first for 8B alignment)
    int2* csr           = (int2*)d_ws;                               // n_edges
    unsigned short* Hb  = (unsigned short*)(csr + n_edges);          // n_nodes*128
    unsigned short* Wp  = Hb + (long long)n_nodes * OUT_DIM;         // 16384
    int* row_ptr        = (int*)(Wp + 16384);                        // n_nodes+1
    int* cursor         = row_ptr + (n_nodes + 2);                   // n_nodes
    int* bsums          = cursor + n_nodes;                          // <=1024

    float* out = (float*)d_out;

    const int egrid = (n_edges + 255) / 256;
    const int ngrid = (n_nodes + 255) / 256;
    const int nscan = (n_nodes + SCAN_B - 1) / SCAN_B;

    // CSR build
    zero_ints<<<ngrid, 256, 0, stream>>>(cursor, n_nodes);
    hist_dst<<<egrid, 256, 0, stream>>>(edge_dst, cursor, n_edges);
    scan_phaseA<<<nscan, SCAN_B, 0, stream>>>(cursor, row_ptr, bsums, n_nodes);
    scan_phaseB<<<1, SCAN_B, 0, stream>>>(bsums, row_ptr, nscan, n_nodes);
    scan_phaseC<<<ngrid, 256, 0, stream>>>(row_ptr, cursor, bsums, n_nodes);
    scatter_edges<<<egrid, 256, 0, stream>>>(edge_src, edge_dst, edge_vals,
                                             cursor, csr, n_edges);

    // Hb = bf16(X @ W)
    pack_w<<<64, 256, 0, stream>>>(weight, Wp);
    int n_strips = (n_nodes + 31) / 32;
    gemm_mfma<<<(n_strips + 3) / 4, 256, 0, stream>>>(features, Wp, Hb, n_nodes);

    // out = bias + sum over incoming edges
    gather_nodes<<<(n_nodes + 3) / 4, 256, 0, stream>>>(
        row_ptr, csr, Hb, bias, out, n_nodes);
}